// Round 8
// baseline (296.306 us; speedup 1.0000x reference)
//
#include <hip/hip_runtime.h>
#include <hip/hip_bf16.h>
#include <stdint.h>

// XL multihead attention, L=S=2048, N=4, E=512, H=8, D=64.  I/O = fp32.
// _rel_shift collapses to a per-row constant (softmax-invariant) => term_bd,
// rel_v, sin_pos_enc, rel_proj_w drop out. Remaining: MHA with rel_u q-bias
// + head-mean att weights.
// R13: attw_k occupancy unlock. Q fragments are 16B-contiguous rows of Qw
// loaded ONCE per head and reused 16x (not the R10 anti-pattern) -> drop the
// Qs LDS entirely (33.3 -> 16.6 KB), halve s-chunk to 128 so grid = 2048
// blocks = 8/CU (was 4), accumulator aw[2][4]. flash/gemms unchanged.

#define L_Q 2048
#define S_K 2048
#define N_B 4
#define E_D 512
#define H_N 8
#define D_H 64

typedef unsigned short u16;
typedef unsigned int u32;
typedef short v8s __attribute__((ext_vector_type(8)));
typedef float v4f __attribute__((ext_vector_type(4)));
typedef float v16f __attribute__((ext_vector_type(16)));
typedef u32 v4u __attribute__((ext_vector_type(4)));

#define MFMA16(a, b, c) __builtin_amdgcn_mfma_f32_16x16x32_bf16(a, b, c, 0, 0, 0)
#define MFMA32(a, b, c) __builtin_amdgcn_mfma_f32_32x32x16_bf16(a, b, c, 0, 0, 0)

// softmax scale folded into Q: exp(s/8) = exp2(sQK) with Q pre-scaled by this
#define QSCALE 0.18033688011112042f  // 0.125 * log2(e)

__device__ __forceinline__ float bf2f(u16 u) {
  unsigned int x = ((unsigned int)u) << 16;
  return __builtin_bit_cast(float, x);
}
__device__ __forceinline__ u16 f2bf(float f) {  // RNE
  unsigned int x = __builtin_bit_cast(unsigned int, f);
  x += 0x7FFFu + ((x >> 16) & 1u);
  return (u16)(x >> 16);
}

// p = exp2(zz), zz already includes the folded softmax scale; clamp +-43.28
// (= exp +-30) keeps everything finite.
__device__ __forceinline__ float expfast(float zz) {
  const float x = __builtin_amdgcn_fmed3f(zz, -43.2809f, 43.2809f);
#if __has_builtin(__builtin_amdgcn_exp2f)
  return __builtin_amdgcn_exp2f(x);
#else
  return __expf(x * 0.6931471805599453f);
#endif
}

// pack two f32 -> u32 of 2 bf16 (lo = first arg), RNE
__device__ __forceinline__ u32 cvtpk(float lo, float hi) {
  u32 r;
  asm("v_cvt_pk_bf16_f32 %0, %1, %2" : "=v"(r) : "v"(lo), "v"(hi));
  return r;
}

// a.upper <-> b.lower (lanes 32-63 of a get b's lanes 0-31, and vice versa)
__device__ __forceinline__ void plswap(u32& a, u32& b) {
  asm volatile("v_permlane32_swap_b32 %0, %1" : "+v"(a), "+v"(b));
}

#if __has_builtin(__builtin_amdgcn_global_load_lds)
#define HAVE_GLDS 1
// dest is wave-uniform base; HW writes lane i at base + i*16B
__device__ __forceinline__ void glds16(const u16* g, u16* l) {
  __builtin_amdgcn_global_load_lds(
      (const __attribute__((address_space(1))) void*)g,
      (__attribute__((address_space(3))) void*)l, 16, 0, 0);
}
#else
#define HAVE_GLDS 0
#endif

// ---- bulk fp32 -> bf16 converter over 8 segments ----
struct Cvt8 {
  const float* s[8];
  u16* d[8];
};
__global__ __launch_bounds__(256) void cvt_k(Cvt8 a) {
  const size_t t = ((size_t)blockIdx.x * 256 + threadIdx.x) * 4;
  const size_t cum[9] = {0,        4194304,  8388608,  12582912, 13369344,
                         13631488, 13633024, 13633536, 13634048};
  if (t >= cum[8]) return;
  int sg = 0;
#pragma unroll
  for (int i = 1; i < 8; i++) sg += (t >= cum[i]);
  const size_t off = t - cum[sg];
  const v4f x = *(const v4f*)(a.s[sg] + off);
  ushort4 o;
  o.x = f2bf(x[0]);
  o.y = f2bf(x[1]);
  o.z = f2bf(x[2]);
  o.w = f2bf(x[3]);
  *(ushort4*)(a.d[sg] + off) = o;
}

// ---------------- NT GEMM core: C(128x128) = A(Mx512) * W(512 rows)^T ------
// BK=32 (proven best). LDS: 4 k-octet planes, stride 1032 shorts. Wave w
// stages plane w via glds width=16 (lane i -> base + i*16B).
__device__ __forceinline__ void gemm_core(const u16* A, const u16* W, int m0,
                                          int n0, u16* As, u16* Bs,
                                          v4f acc[4][4]) {
  const int lane = threadIdx.x & 63;
  const int w = threadIdx.x >> 6;
  const int wr = w >> 1, wc = w & 1;
  const int q = lane >> 4, c = lane & 15;
#pragma unroll
  for (int i = 0; i < 4; i++)
#pragma unroll
    for (int j = 0; j < 4; j++) acc[i][j] = (v4f){0.f, 0.f, 0.f, 0.f};
  for (int kk = 0; kk < 16; ++kk) {
    const u16* ga = A + (size_t)(m0 + lane) * E_D + kk * 32 + w * 8;
    const u16* gb = W + (size_t)(n0 + lane) * E_D + kk * 32 + w * 8;
#if HAVE_GLDS
    __syncthreads();  // prior iteration's reads done before overwrite
    glds16(ga, As + w * 1032);
    glds16(ga + 64 * E_D, As + w * 1032 + 512);
    glds16(gb, Bs + w * 1032);
    glds16(gb + 64 * E_D, Bs + w * 1032 + 512);
    __syncthreads();  // drains vmcnt -> LDS ready
#else
    const v8s va0 = *(const v8s*)ga;
    const v8s va1 = *(const v8s*)(ga + 64 * E_D);
    const v8s vb0 = *(const v8s*)gb;
    const v8s vb1 = *(const v8s*)(gb + 64 * E_D);
    __syncthreads();
    *(v8s*)(As + w * 1032 + lane * 8) = va0;
    *(v8s*)(As + w * 1032 + 512 + lane * 8) = va1;
    *(v8s*)(Bs + w * 1032 + lane * 8) = vb0;
    *(v8s*)(Bs + w * 1032 + 512 + lane * 8) = vb1;
    __syncthreads();
#endif
    v8s a[4], b[4];
#pragma unroll
    for (int i = 0; i < 4; i++)
      a[i] = *(const v8s*)(As + q * 1032 + (wr * 64 + i * 16 + c) * 8);
#pragma unroll
    for (int j = 0; j < 4; j++)
      b[j] = *(const v8s*)(Bs + q * 1032 + (wc * 64 + j * 16 + c) * 8);
#pragma unroll
    for (int i = 0; i < 4; i++)
#pragma unroll
      for (int j = 0; j < 4; j++) acc[i][j] = MFMA16(a[i], b[j], acc[i][j]);
  }
}

// qkv projections (all-bf16). z=0: Qw[n][h][l][d] = (q + bias + rel_u)*QSCALE
//   z=1: Kw[n][h][s][d]   z=2: Vt[n][h][d][s] (transposed for PV)
__global__ __launch_bounds__(256) void gemm_qkv(
    const u16* __restrict__ qb, const u16* __restrict__ kb,
    const u16* __restrict__ vb, const u16* __restrict__ Wallb,
    const u16* __restrict__ biasb, const u16* __restrict__ rel_ub,
    u16* __restrict__ Qw, u16* __restrict__ Kw, u16* __restrict__ Vt) {
  __shared__ __align__(16) u16 As[4 * 1032];
  __shared__ __align__(16) u16 Bs[4 * 1032];
  const int z = blockIdx.z;
  const u16* A = (z == 0) ? qb : ((z == 1) ? kb : vb);
  const int m0 = blockIdx.x * 128, n0 = blockIdx.y * 128;
  v4f acc[4][4];
  gemm_core(A, Wallb + (size_t)z * E_D * E_D, m0, n0, As, Bs, acc);
  const int lane = threadIdx.x & 63, w = threadIdx.x >> 6;
  const int wr = w >> 1, wc = w & 1;
  const int q = lane >> 4, c = lane & 15;
  const float scale = (z == 0) ? QSCALE : 1.0f;
#pragma unroll
  for (int j = 0; j < 4; j++) {
    const int jg = n0 + wc * 64 + j * 16 + c;  // output feature = h*64+d
    const int h = jg >> 6, d = jg & 63;
    float add =
        bf2f(biasb[z * E_D + jg]) + ((z == 0) ? bf2f(rel_ub[jg]) : 0.f);
#pragma unroll
    for (int i = 0; i < 4; i++) {
#pragma unroll
      for (int r = 0; r < 4; r++) {
        const int mg = m0 + wr * 64 + i * 16 + q * 4 + r;  // row = l*4+n
        const int row = mg >> 2, nn = mg & 3;
        const u16 o = f2bf((acc[i][j][r] + add) * scale);
        if (z == 0)
          Qw[((size_t)(nn * H_N + h) * L_Q + row) * D_H + d] = o;
        else if (z == 1)
          Kw[((size_t)(nn * H_N + h) * S_K + row) * D_H + d] = o;
        else
          Vt[((size_t)(nn * H_N + h) * D_H + d) * S_K + row] = o;
      }
    }
  }
}

// out = Actx(8192x512)bf16 @ Woutb^T + bout -> fp32 d_out[0 : L*N*E)
__global__ __launch_bounds__(256) void gemm_out(const u16* __restrict__ Actx,
                                                const u16* __restrict__ Woutb,
                                                const u16* __restrict__ boutb,
                                                float* __restrict__ out) {
  __shared__ __align__(16) u16 As[4 * 1032];
  __shared__ __align__(16) u16 Bs[4 * 1032];
  const int m0 = blockIdx.x * 128, n0 = blockIdx.y * 128;
  v4f acc[4][4];
  gemm_core(Actx, Woutb, m0, n0, As, Bs, acc);
  const int lane = threadIdx.x & 63, w = threadIdx.x >> 6;
  const int wr = w >> 1, wc = w & 1;
  const int q = lane >> 4, c = lane & 15;
#pragma unroll
  for (int j = 0; j < 4; j++) {
    const int jg = n0 + wc * 64 + j * 16 + c;
    const float bb = bf2f(boutb[jg]);
#pragma unroll
    for (int i = 0; i < 4; i++) {
#pragma unroll
      for (int r = 0; r < 4; r++) {
        const int mg = m0 + wr * 64 + i * 16 + q * 4 + r;
        out[(size_t)mg * E_D + jg] = acc[i][j][r] + bb;
      }
    }
  }
}

// Flash pass, 32x32x16 form. Block = 128 l (32 per wave), chunk = 64 s.
// QK^T as mfma(K,Q) => D = S^T[s][l], lane holds 32 s-values for its own l.
// P in-register: expfast -> cvt_pk bf16 pairs -> permlane32_swap builds the
// PV B-operand. PV: O^T[d][l] = V^T[d][s] @ P^T[s][l].
// Double-buffered Ks/Vs (1 barrier/chunk) + next-chunk K/V reg prefetch.
__global__ __launch_bounds__(256) void flash_pv(
    const u16* __restrict__ Qw, const u16* __restrict__ Kw,
    const u16* __restrict__ Vt, u16* __restrict__ Actx,
    float* __restrict__ Rbuf) {
  __shared__ __align__(16) u16 Ks[2][8 * 520];  // plane = d-octet, idx = s
  __shared__ __align__(16) u16 Vs[2][8 * 520];  // plane = s-octet, idx = d
  const int lane = threadIdx.x & 63, w = threadIdx.x >> 6;
  const int ln = lane & 31, hi = lane >> 5;
  // bijective XCD swizzle: 512 blocks = 8 xcd * 64; xcd gets 4 contig nh's
  const int orig = (blockIdx.x & 7) * 64 + (blockIdx.x >> 3);
  const int l0 = (orig & 15) * 128;
  const int h = (orig >> 4) & 7;
  const int n = orig >> 7;
  const int nh = n * H_N + h;
  // Q B-fragments direct from global (row l, k = d = kt*16 + hi*8 + j)
  v8s aq[4];
  {
    const u16* gq = Qw + ((size_t)nh * L_Q + l0 + w * 32 + ln) * D_H + hi * 8;
#pragma unroll
    for (int kt = 0; kt < 4; kt++) aq[kt] = *(const v8s*)(gq + kt * 16);
  }
  v16f ctx[2];
  ctx[0] = (v16f)0.f;
  ctx[1] = (v16f)0.f;
  float s_run = 0.f;
  // prefetch chunk 0 into regs
  const u16* gk = Kw + ((size_t)nh * S_K + lane) * D_H + w * 8;
  const u16* gv = Vt + ((size_t)nh * D_H + lane) * S_K + w * 8;
  v8s vk0 = *(const v8s*)gk;
  v8s vk1 = *(const v8s*)(gk + 32);
  v8s vv0 = *(const v8s*)gv;
  v8s vv1 = *(const v8s*)(gv + 32);
  int p = 0;
  for (int s0 = 0; s0 < S_K; s0 += 64, p ^= 1) {
    // stage current chunk (regs -> LDS buf p); prior reads of buf p finished
    // before the previous barrier
    *(v8s*)(Ks[p] + w * 520 + lane * 8) = vk0;
    *(v8s*)(Ks[p] + (w + 4) * 520 + lane * 8) = vk1;
    *(v8s*)(Vs[p] + w * 520 + lane * 8) = vv0;
    *(v8s*)(Vs[p] + (w + 4) * 520 + lane * 8) = vv1;
    __syncthreads();
    // issue next chunk's loads; latency hides under this chunk's compute
    if (s0 + 64 < S_K) {
      gk += 64 * D_H;  // next 64 s-rows
      gv += 64;        // next 64 s-cols
      vk0 = *(const v8s*)gk;
      vk1 = *(const v8s*)(gk + 32);
      vv0 = *(const v8s*)gv;
      vv1 = *(const v8s*)(gv + 32);
    }
    // QK: two 32-s tiles; A = K[s][d] (row=ln), B = Q (col=ln)
    v8s pb[4];  // PV B-frags: P^T slot ks covers s = ks*16 + hi*8 + j
#pragma unroll
    for (int st = 0; st < 2; st++) {
      v16f zz = (v16f)0.f;
#pragma unroll
      for (int kt = 0; kt < 4; kt++) {
        const v8s bk =
            *(const v8s*)(Ks[p] + (kt * 2 + hi) * 520 + (st * 32 + ln) * 8);
        zz = MFMA32(bk, aq[kt], zz);
      }
      // lane's s-coverage: st*32 + (r&3) + 8*(r>>2) + 4*hi, r = 0..15
      float pv[16];
#pragma unroll
      for (int r = 0; r < 16; r++) {
        pv[r] = expfast(zz[r]);
        s_run += pv[r];
      }
#pragma unroll
      for (int half = 0; half < 2; half++) {
        const int rb = half * 8;
        u32 a0 = cvtpk(pv[rb + 0], pv[rb + 1]);
        u32 b0 = cvtpk(pv[rb + 4], pv[rb + 5]);
        u32 a1 = cvtpk(pv[rb + 2], pv[rb + 3]);
        u32 b1 = cvtpk(pv[rb + 6], pv[rb + 7]);
        plswap(a0, b0);  // a0 -> word0 (s+0,1|8,9), b0 -> word2 (s+4,5|12,13)
        plswap(a1, b1);  // a1 -> word1,  b1 -> word3
        v4u t;
        t.x = a0;
        t.y = a1;
        t.z = b0;
        t.w = b1;
        pb[st * 2 + half] = __builtin_bit_cast(v8s, t);
      }
    }
    // PV: O^T[d][l]; A = V^T[d][s] (row=ln), B = P^T (col=ln)
#pragma unroll
    for (int dt = 0; dt < 2; dt++) {
#pragma unroll
      for (int ks = 0; ks < 4; ks++) {
        const v8s av =
            *(const v8s*)(Vs[p] + (ks * 2 + hi) * 520 + (dt * 32 + ln) * 8);
        ctx[dt] = MFMA32(av, pb[ks], ctx[dt]);
      }
    }
  }
  // full row sum: lane covers half the s-values, partner lane^32 the rest
  const float s = s_run + __shfl_xor(s_run, 32);
  const float rr = 1.0f / s;
  const int l = l0 + w * 32 + ln;
  u16* pout = Actx + ((size_t)l * N_B + n) * E_D + h * D_H;
#pragma unroll
  for (int dt = 0; dt < 2; dt++) {
#pragma unroll
    for (int g = 0; g < 4; g++) {
      const int d = dt * 32 + g * 8 + hi * 4;  // 4 consecutive d per group
      uint2 o;
      o.x = cvtpk(ctx[dt][g * 4 + 0] * rr, ctx[dt][g * 4 + 1] * rr);
      o.y = cvtpk(ctx[dt][g * 4 + 2] * rr, ctx[dt][g * 4 + 3] * rr);
      *(uint2*)(pout + d) = o;
    }
  }
  if (hi == 0) Rbuf[(size_t)nh * L_Q + l] = rr;  // 32 consecutive floats
}

// attw pass (runs LAST; overwrites the d_out scratch region with the real
// attention-weight output): per (n, l-tile 64, s-chunk 128): loop 8 heads x
// 2 half-chunks. Q fragments DIRECT from global (16B/lane, L1-resident,
// loaded once per h, reused 16x) -- no Qs LDS. Ks[2] double-buffer only
// (16.6 KB -> 8 blocks/CU with the 2048-block grid). aw[2][4] static
// indices (rule #20). 1 barrier/iter + reg prefetch of next K chunk.
__global__ __launch_bounds__(256) void attw_k(const u16* __restrict__ Qw,
                                              const u16* __restrict__ Kw,
                                              const float* __restrict__ Rbuf,
                                              float* __restrict__ AW) {
  __shared__ __align__(16) u16 Ks[2][8 * 520];
  const int lane = threadIdx.x & 63, w = threadIdx.x >> 6;
  const int q = lane >> 4, c = lane & 15;
  const int s_base = blockIdx.x * 128;
  const int l0 = blockIdx.y * 64;
  const int n = blockIdx.z;
  v4f aw[2][4];
#pragma unroll
  for (int half = 0; half < 2; half++)
#pragma unroll
    for (int jt = 0; jt < 4; jt++) aw[half][jt] = (v4f){0.f, 0.f, 0.f, 0.f};
  // prologue prefetch: (h=0, half=0) K chunk
  v8s vk0, vk1;
  {
    const u16* gk =
        Kw + ((size_t)(n * H_N) * S_K + s_base + lane) * D_H + w * 8;
    vk0 = *(const v8s*)gk;
    vk1 = *(const v8s*)(gk + 32);
  }
  for (int h = 0; h < H_N; ++h) {
    const int nh = n * H_N + h;
    // Q A-fragment direct from global: row l = l0+w*16+c, k = q*8 (+32)
    const u16* gq = Qw + ((size_t)nh * L_Q + l0 + w * 16 + c) * D_H + q * 8;
    const v8s aq0 = *(const v8s*)gq;
    const v8s aq1 = *(const v8s*)(gq + 32);
    float rr[4];
#pragma unroll
    for (int r = 0; r < 4; r++)
      rr[r] = Rbuf[(size_t)nh * L_Q + l0 + w * 16 + q * 4 + r];
#pragma unroll
    for (int half = 0; half < 2; ++half) {  // static: aw indices compile-time
      const int p = half;  // iter = h*2+half; parity = half (compile-time)
      // stage current K chunk
      *(v8s*)(Ks[p] + w * 520 + lane * 8) = vk0;
      *(v8s*)(Ks[p] + (w + 4) * 520 + lane * 8) = vk1;
      __syncthreads();
      // prefetch next (h, half) chunk's K
      if (h * 2 + half + 1 < 16) {
        const int h2 = (half == 1) ? h + 1 : h;
        const int hf2 = (half == 1) ? 0 : 1;
        const u16* gk =
            Kw +
            ((size_t)(n * H_N + h2) * S_K + s_base + hf2 * 64 + lane) * D_H +
            w * 8;
        vk0 = *(const v8s*)gk;
        vk1 = *(const v8s*)(gk + 32);
      }
#pragma unroll
      for (int jt = 0; jt < 4; jt++) {
        const v8s bk0 = *(const v8s*)(Ks[p] + q * 520 + (jt * 16 + c) * 8);
        const v8s bk1 =
            *(const v8s*)(Ks[p] + (q + 4) * 520 + (jt * 16 + c) * 8);
        v4f zz = (v4f){0.f, 0.f, 0.f, 0.f};
        zz = MFMA16(aq0, bk0, zz);
        zz = MFMA16(aq1, bk1, zz);
#pragma unroll
        for (int r = 0; r < 4; r++) aw[half][jt][r] += expfast(zz[r]) * rr[r];
      }
    }
  }
#pragma unroll
  for (int half = 0; half < 2; half++)
#pragma unroll
    for (int jt = 0; jt < 4; jt++)
#pragma unroll
      for (int r = 0; r < 4; r++) {
        const int l = l0 + w * 16 + q * 4 + r;
        const int s = s_base + half * 64 + jt * 16 + c;
        AW[((size_t)n * L_Q + l) * S_K + s] = aw[half][jt][r] * 0.125f;
      }
}

extern "C" void kernel_launch(void* const* d_in, const int* in_sizes, int n_in,
                              void* d_out, int out_size, void* d_ws,
                              size_t ws_size, hipStream_t stream) {
  // ws layout (<= 29.7 MB, proven safe at 33.8 in R4)
  char* ws = (char*)d_ws;
  u16* Wallb = (u16*)(ws);                 // 1.57 MB
  u16* Woutb = (u16*)(ws + 1572864);       // 0.52 MB
  u16* biasb = (u16*)(ws + 2097152);       // 3 KB
  u16* boutb = (u16*)(ws + 2100224);       // 1 KB
  u16* rel_ub = (u16*)(ws + 2101248);      // 1 KB
  u16* Qw = (u16*)(ws + 4194304);          // 8 MB (N,H,L,D)
  u16* Kw = (u16*)(ws + 12582912);         // 8 MB (N,H,S,D)
  u16* Vt = (u16*)(ws + 20971520);         // 8 MB (N,H,D,S)
  float* Rbuf = (float*)(ws + 29360128);   // 256 KB (N*H, L)

  // scratch inside d_out's attw region (67 MB; overwritten by attw_k LAST)
  float* out = (float*)d_out;
  char* sc = (char*)d_out + 16777216;
  u16* qb = (u16*)(sc);              // 8 MB converted query
  u16* kb = (u16*)(sc + 8388608);    // 8 MB converted key
  u16* vb = (u16*)(sc + 16777216);   // 8 MB converted value
  u16* Actx = (u16*)(sc + 25165824); // 8 MB context (L*4+n, E)
  float* AW = out + (size_t)L_Q * N_B * E_D;

  Cvt8 a;
  a.s[0] = (const float*)d_in[0];  a.d[0] = qb;      // query
  a.s[1] = (const float*)d_in[1];  a.d[1] = kb;      // key
  a.s[2] = (const float*)d_in[2];  a.d[2] = vb;      // value
  a.s[3] = (const float*)d_in[4];  a.d[3] = Wallb;   // in_proj_weight
  a.s[4] = (const float*)d_in[6];  a.d[4] = Woutb;   // out_w
  a.s[5] = (const float*)d_in[5];  a.d[5] = biasb;   // in_proj_bias
  a.s[6] = (const float*)d_in[7];  a.d[6] = boutb;   // out_b
  a.s[7] = (const float*)d_in[9];  a.d[7] = rel_ub;  // rel_u
  // d_in[3] sin_pos_enc, d_in[8] rel_proj_w, d_in[10] rel_v: algebraically out

  hipLaunchKernelGGL(cvt_k, dim3(13315), dim3(256), 0, stream, a);
  hipLaunchKernelGGL(gemm_qkv, dim3(64, 4, 3), dim3(256), 0, stream, qb, kb,
                     vb, Wallb, biasb, rel_ub, Qw, Kw, Vt);
  hipLaunchKernelGGL(flash_pv, dim3(512), dim3(256), 0, stream, Qw, Kw, Vt,
                     Actx, Rbuf);
  hipLaunchKernelGGL(gemm_out, dim3(64, 4, 1), dim3(256), 0, stream, Actx,
                     Woutb, boutb, out);
  hipLaunchKernelGGL(attw_k, dim3(16, 32, 4), dim3(256), 0, stream, Qw, Kw,
                     Rbuf, AW);
}

// Round 9
// 285.835 us; speedup vs baseline: 1.0366x; 1.0366x over previous
//
#include <hip/hip_runtime.h>
#include <hip/hip_bf16.h>
#include <stdint.h>

// XL multihead attention, L=S=2048, N=4, E=512, H=8, D=64.  I/O = fp32.
// _rel_shift collapses to a per-row constant (softmax-invariant) => term_bd,
// rel_v, sin_pos_enc, rel_proj_w drop out. Remaining: MHA with rel_u q-bias
// + head-mean att weights.
// R14: attw_k = R12 shape (s-chunk 256, Qs LDS, aw[4][4]) + DEPTH-2 K
// prefetch (reg sets A/B): stage chunk i from set i&1, refill with chunk
// i+2 -> load->use distance ~2 iterations covers L2 latency. R13 taught:
// occupancy knobs don't move attw (19% across all variants); the stall is
// exposed K-load latency inside the 170-cycle barrier round.

#define L_Q 2048
#define S_K 2048
#define N_B 4
#define E_D 512
#define H_N 8
#define D_H 64

typedef unsigned short u16;
typedef unsigned int u32;
typedef short v8s __attribute__((ext_vector_type(8)));
typedef float v4f __attribute__((ext_vector_type(4)));
typedef float v16f __attribute__((ext_vector_type(16)));
typedef u32 v4u __attribute__((ext_vector_type(4)));

#define MFMA16(a, b, c) __builtin_amdgcn_mfma_f32_16x16x32_bf16(a, b, c, 0, 0, 0)
#define MFMA32(a, b, c) __builtin_amdgcn_mfma_f32_32x32x16_bf16(a, b, c, 0, 0, 0)

// softmax scale folded into Q: exp(s/8) = exp2(sQK) with Q pre-scaled by this
#define QSCALE 0.18033688011112042f  // 0.125 * log2(e)

__device__ __forceinline__ float bf2f(u16 u) {
  unsigned int x = ((unsigned int)u) << 16;
  return __builtin_bit_cast(float, x);
}
__device__ __forceinline__ u16 f2bf(float f) {  // RNE
  unsigned int x = __builtin_bit_cast(unsigned int, f);
  x += 0x7FFFu + ((x >> 16) & 1u);
  return (u16)(x >> 16);
}

// p = exp2(zz), zz already includes the folded softmax scale; clamp +-43.28
// (= exp +-30) keeps everything finite.
__device__ __forceinline__ float expfast(float zz) {
  const float x = __builtin_amdgcn_fmed3f(zz, -43.2809f, 43.2809f);
#if __has_builtin(__builtin_amdgcn_exp2f)
  return __builtin_amdgcn_exp2f(x);
#else
  return __expf(x * 0.6931471805599453f);
#endif
}

// pack two f32 -> u32 of 2 bf16 (lo = first arg), RNE
__device__ __forceinline__ u32 cvtpk(float lo, float hi) {
  u32 r;
  asm("v_cvt_pk_bf16_f32 %0, %1, %2" : "=v"(r) : "v"(lo), "v"(hi));
  return r;
}

// a.upper <-> b.lower (lanes 32-63 of a get b's lanes 0-31, and vice versa)
__device__ __forceinline__ void plswap(u32& a, u32& b) {
  asm volatile("v_permlane32_swap_b32 %0, %1" : "+v"(a), "+v"(b));
}

#if __has_builtin(__builtin_amdgcn_global_load_lds)
#define HAVE_GLDS 1
// dest is wave-uniform base; HW writes lane i at base + i*16B
__device__ __forceinline__ void glds16(const u16* g, u16* l) {
  __builtin_amdgcn_global_load_lds(
      (const __attribute__((address_space(1))) void*)g,
      (__attribute__((address_space(3))) void*)l, 16, 0, 0);
}
#else
#define HAVE_GLDS 0
#endif

// ---- bulk fp32 -> bf16 converter over 8 segments ----
struct Cvt8 {
  const float* s[8];
  u16* d[8];
};
__global__ __launch_bounds__(256) void cvt_k(Cvt8 a) {
  const size_t t = ((size_t)blockIdx.x * 256 + threadIdx.x) * 4;
  const size_t cum[9] = {0,        4194304,  8388608,  12582912, 13369344,
                         13631488, 13633024, 13633536, 13634048};
  if (t >= cum[8]) return;
  int sg = 0;
#pragma unroll
  for (int i = 1; i < 8; i++) sg += (t >= cum[i]);
  const size_t off = t - cum[sg];
  const v4f x = *(const v4f*)(a.s[sg] + off);
  ushort4 o;
  o.x = f2bf(x[0]);
  o.y = f2bf(x[1]);
  o.z = f2bf(x[2]);
  o.w = f2bf(x[3]);
  *(ushort4*)(a.d[sg] + off) = o;
}

// ---------------- NT GEMM core: C(128x128) = A(Mx512) * W(512 rows)^T ------
// BK=32 (proven best). LDS: 4 k-octet planes, stride 1032 shorts. Wave w
// stages plane w via glds width=16 (lane i -> base + i*16B).
__device__ __forceinline__ void gemm_core(const u16* A, const u16* W, int m0,
                                          int n0, u16* As, u16* Bs,
                                          v4f acc[4][4]) {
  const int lane = threadIdx.x & 63;
  const int w = threadIdx.x >> 6;
  const int wr = w >> 1, wc = w & 1;
  const int q = lane >> 4, c = lane & 15;
#pragma unroll
  for (int i = 0; i < 4; i++)
#pragma unroll
    for (int j = 0; j < 4; j++) acc[i][j] = (v4f){0.f, 0.f, 0.f, 0.f};
  for (int kk = 0; kk < 16; ++kk) {
    const u16* ga = A + (size_t)(m0 + lane) * E_D + kk * 32 + w * 8;
    const u16* gb = W + (size_t)(n0 + lane) * E_D + kk * 32 + w * 8;
#if HAVE_GLDS
    __syncthreads();  // prior iteration's reads done before overwrite
    glds16(ga, As + w * 1032);
    glds16(ga + 64 * E_D, As + w * 1032 + 512);
    glds16(gb, Bs + w * 1032);
    glds16(gb + 64 * E_D, Bs + w * 1032 + 512);
    __syncthreads();  // drains vmcnt -> LDS ready
#else
    const v8s va0 = *(const v8s*)ga;
    const v8s va1 = *(const v8s*)(ga + 64 * E_D);
    const v8s vb0 = *(const v8s*)gb;
    const v8s vb1 = *(const v8s*)(gb + 64 * E_D);
    __syncthreads();
    *(v8s*)(As + w * 1032 + lane * 8) = va0;
    *(v8s*)(As + w * 1032 + 512 + lane * 8) = va1;
    *(v8s*)(Bs + w * 1032 + lane * 8) = vb0;
    *(v8s*)(Bs + w * 1032 + 512 + lane * 8) = vb1;
    __syncthreads();
#endif
    v8s a[4], b[4];
#pragma unroll
    for (int i = 0; i < 4; i++)
      a[i] = *(const v8s*)(As + q * 1032 + (wr * 64 + i * 16 + c) * 8);
#pragma unroll
    for (int j = 0; j < 4; j++)
      b[j] = *(const v8s*)(Bs + q * 1032 + (wc * 64 + j * 16 + c) * 8);
#pragma unroll
    for (int i = 0; i < 4; i++)
#pragma unroll
      for (int j = 0; j < 4; j++) acc[i][j] = MFMA16(a[i], b[j], acc[i][j]);
  }
}

// qkv projections (all-bf16). z=0: Qw[n][h][l][d] = (q + bias + rel_u)*QSCALE
//   z=1: Kw[n][h][s][d]   z=2: Vt[n][h][d][s] (transposed for PV)
__global__ __launch_bounds__(256) void gemm_qkv(
    const u16* __restrict__ qb, const u16* __restrict__ kb,
    const u16* __restrict__ vb, const u16* __restrict__ Wallb,
    const u16* __restrict__ biasb, const u16* __restrict__ rel_ub,
    u16* __restrict__ Qw, u16* __restrict__ Kw, u16* __restrict__ Vt) {
  __shared__ __align__(16) u16 As[4 * 1032];
  __shared__ __align__(16) u16 Bs[4 * 1032];
  const int z = blockIdx.z;
  const u16* A = (z == 0) ? qb : ((z == 1) ? kb : vb);
  const int m0 = blockIdx.x * 128, n0 = blockIdx.y * 128;
  v4f acc[4][4];
  gemm_core(A, Wallb + (size_t)z * E_D * E_D, m0, n0, As, Bs, acc);
  const int lane = threadIdx.x & 63, w = threadIdx.x >> 6;
  const int wr = w >> 1, wc = w & 1;
  const int q = lane >> 4, c = lane & 15;
  const float scale = (z == 0) ? QSCALE : 1.0f;
#pragma unroll
  for (int j = 0; j < 4; j++) {
    const int jg = n0 + wc * 64 + j * 16 + c;  // output feature = h*64+d
    const int h = jg >> 6, d = jg & 63;
    float add =
        bf2f(biasb[z * E_D + jg]) + ((z == 0) ? bf2f(rel_ub[jg]) : 0.f);
#pragma unroll
    for (int i = 0; i < 4; i++) {
#pragma unroll
      for (int r = 0; r < 4; r++) {
        const int mg = m0 + wr * 64 + i * 16 + q * 4 + r;  // row = l*4+n
        const int row = mg >> 2, nn = mg & 3;
        const u16 o = f2bf((acc[i][j][r] + add) * scale);
        if (z == 0)
          Qw[((size_t)(nn * H_N + h) * L_Q + row) * D_H + d] = o;
        else if (z == 1)
          Kw[((size_t)(nn * H_N + h) * S_K + row) * D_H + d] = o;
        else
          Vt[((size_t)(nn * H_N + h) * D_H + d) * S_K + row] = o;
      }
    }
  }
}

// out = Actx(8192x512)bf16 @ Woutb^T + bout -> fp32 d_out[0 : L*N*E)
__global__ __launch_bounds__(256) void gemm_out(const u16* __restrict__ Actx,
                                                const u16* __restrict__ Woutb,
                                                const u16* __restrict__ boutb,
                                                float* __restrict__ out) {
  __shared__ __align__(16) u16 As[4 * 1032];
  __shared__ __align__(16) u16 Bs[4 * 1032];
  const int m0 = blockIdx.x * 128, n0 = blockIdx.y * 128;
  v4f acc[4][4];
  gemm_core(Actx, Woutb, m0, n0, As, Bs, acc);
  const int lane = threadIdx.x & 63, w = threadIdx.x >> 6;
  const int wr = w >> 1, wc = w & 1;
  const int q = lane >> 4, c = lane & 15;
#pragma unroll
  for (int j = 0; j < 4; j++) {
    const int jg = n0 + wc * 64 + j * 16 + c;
    const float bb = bf2f(boutb[jg]);
#pragma unroll
    for (int i = 0; i < 4; i++) {
#pragma unroll
      for (int r = 0; r < 4; r++) {
        const int mg = m0 + wr * 64 + i * 16 + q * 4 + r;
        out[(size_t)mg * E_D + jg] = acc[i][j][r] + bb;
      }
    }
  }
}

// Flash pass, 32x32x16 form. Block = 128 l (32 per wave), chunk = 64 s.
// QK^T as mfma(K,Q) => D = S^T[s][l], lane holds 32 s-values for its own l.
// P in-register: expfast -> cvt_pk bf16 pairs -> permlane32_swap builds the
// PV B-operand. PV: O^T[d][l] = V^T[d][s] @ P^T[s][l].
// Double-buffered Ks/Vs (1 barrier/chunk) + next-chunk K/V reg prefetch.
__global__ __launch_bounds__(256) void flash_pv(
    const u16* __restrict__ Qw, const u16* __restrict__ Kw,
    const u16* __restrict__ Vt, u16* __restrict__ Actx,
    float* __restrict__ Rbuf) {
  __shared__ __align__(16) u16 Ks[2][8 * 520];  // plane = d-octet, idx = s
  __shared__ __align__(16) u16 Vs[2][8 * 520];  // plane = s-octet, idx = d
  const int lane = threadIdx.x & 63, w = threadIdx.x >> 6;
  const int ln = lane & 31, hi = lane >> 5;
  // bijective XCD swizzle: 512 blocks = 8 xcd * 64; xcd gets 4 contig nh's
  const int orig = (blockIdx.x & 7) * 64 + (blockIdx.x >> 3);
  const int l0 = (orig & 15) * 128;
  const int h = (orig >> 4) & 7;
  const int n = orig >> 7;
  const int nh = n * H_N + h;
  // Q B-fragments direct from global (row l, k = d = kt*16 + hi*8 + j)
  v8s aq[4];
  {
    const u16* gq = Qw + ((size_t)nh * L_Q + l0 + w * 32 + ln) * D_H + hi * 8;
#pragma unroll
    for (int kt = 0; kt < 4; kt++) aq[kt] = *(const v8s*)(gq + kt * 16);
  }
  v16f ctx[2];
  ctx[0] = (v16f)0.f;
  ctx[1] = (v16f)0.f;
  float s_run = 0.f;
  // prefetch chunk 0 into regs
  const u16* gk = Kw + ((size_t)nh * S_K + lane) * D_H + w * 8;
  const u16* gv = Vt + ((size_t)nh * D_H + lane) * S_K + w * 8;
  v8s vk0 = *(const v8s*)gk;
  v8s vk1 = *(const v8s*)(gk + 32);
  v8s vv0 = *(const v8s*)gv;
  v8s vv1 = *(const v8s*)(gv + 32);
  int p = 0;
  for (int s0 = 0; s0 < S_K; s0 += 64, p ^= 1) {
    // stage current chunk (regs -> LDS buf p); prior reads of buf p finished
    // before the previous barrier
    *(v8s*)(Ks[p] + w * 520 + lane * 8) = vk0;
    *(v8s*)(Ks[p] + (w + 4) * 520 + lane * 8) = vk1;
    *(v8s*)(Vs[p] + w * 520 + lane * 8) = vv0;
    *(v8s*)(Vs[p] + (w + 4) * 520 + lane * 8) = vv1;
    __syncthreads();
    // issue next chunk's loads; latency hides under this chunk's compute
    if (s0 + 64 < S_K) {
      gk += 64 * D_H;  // next 64 s-rows
      gv += 64;        // next 64 s-cols
      vk0 = *(const v8s*)gk;
      vk1 = *(const v8s*)(gk + 32);
      vv0 = *(const v8s*)gv;
      vv1 = *(const v8s*)(gv + 32);
    }
    // QK: two 32-s tiles; A = K[s][d] (row=ln), B = Q (col=ln)
    v8s pb[4];  // PV B-frags: P^T slot ks covers s = ks*16 + hi*8 + j
#pragma unroll
    for (int st = 0; st < 2; st++) {
      v16f zz = (v16f)0.f;
#pragma unroll
      for (int kt = 0; kt < 4; kt++) {
        const v8s bk =
            *(const v8s*)(Ks[p] + (kt * 2 + hi) * 520 + (st * 32 + ln) * 8);
        zz = MFMA32(bk, aq[kt], zz);
      }
      // lane's s-coverage: st*32 + (r&3) + 8*(r>>2) + 4*hi, r = 0..15
      float pv[16];
#pragma unroll
      for (int r = 0; r < 16; r++) {
        pv[r] = expfast(zz[r]);
        s_run += pv[r];
      }
#pragma unroll
      for (int half = 0; half < 2; half++) {
        const int rb = half * 8;
        u32 a0 = cvtpk(pv[rb + 0], pv[rb + 1]);
        u32 b0 = cvtpk(pv[rb + 4], pv[rb + 5]);
        u32 a1 = cvtpk(pv[rb + 2], pv[rb + 3]);
        u32 b1 = cvtpk(pv[rb + 6], pv[rb + 7]);
        plswap(a0, b0);  // a0 -> word0 (s+0,1|8,9), b0 -> word2 (s+4,5|12,13)
        plswap(a1, b1);  // a1 -> word1,  b1 -> word3
        v4u t;
        t.x = a0;
        t.y = a1;
        t.z = b0;
        t.w = b1;
        pb[st * 2 + half] = __builtin_bit_cast(v8s, t);
      }
    }
    // PV: O^T[d][l]; A = V^T[d][s] (row=ln), B = P^T (col=ln)
#pragma unroll
    for (int dt = 0; dt < 2; dt++) {
#pragma unroll
      for (int ks = 0; ks < 4; ks++) {
        const v8s av =
            *(const v8s*)(Vs[p] + (ks * 2 + hi) * 520 + (dt * 32 + ln) * 8);
        ctx[dt] = MFMA32(av, pb[ks], ctx[dt]);
      }
    }
  }
  // full row sum: lane covers half the s-values, partner lane^32 the rest
  const float s = s_run + __shfl_xor(s_run, 32);
  const float rr = 1.0f / s;
  const int l = l0 + w * 32 + ln;
  u16* pout = Actx + ((size_t)l * N_B + n) * E_D + h * D_H;
#pragma unroll
  for (int dt = 0; dt < 2; dt++) {
#pragma unroll
    for (int g = 0; g < 4; g++) {
      const int d = dt * 32 + g * 8 + hi * 4;  // 4 consecutive d per group
      uint2 o;
      o.x = cvtpk(ctx[dt][g * 4 + 0] * rr, ctx[dt][g * 4 + 1] * rr);
      o.y = cvtpk(ctx[dt][g * 4 + 2] * rr, ctx[dt][g * 4 + 3] * rr);
      *(uint2*)(pout + d) = o;
    }
  }
  if (hi == 0) Rbuf[(size_t)nh * L_Q + l] = rr;  // 32 consecutive floats
}

// attw pass (runs LAST; overwrites the d_out scratch region with the real
// attention-weight output): per (n, l-tile 64, s-chunk 256): loop h
// (runtime, addresses only) with fully unrolled ss (aw indices compile-time,
// rule #20). DEPTH-2 K prefetch: reg sets A (even ss) / B (odd ss); stage
// chunk i, then refill its set with chunk i+2 -> ~2-iteration load->use
// distance covers L2 latency. Q prefetched 2 iters before its staging.
__global__ __launch_bounds__(256) void attw_k(const u16* __restrict__ Qw,
                                              const u16* __restrict__ Kw,
                                              const float* __restrict__ Rbuf,
                                              float* __restrict__ AW) {
  __shared__ __align__(16) u16 Qs[2][8 * 520];
  __shared__ __align__(16) u16 Ks[2][8 * 520];
  const int lane = threadIdx.x & 63, w = threadIdx.x >> 6;
  const int q = lane >> 4, c = lane & 15;
  const int s_base = blockIdx.x * 256;
  const int l0 = blockIdx.y * 64;
  const int n = blockIdx.z;
  v4f aw[4][4];
#pragma unroll
  for (int ss = 0; ss < 4; ss++)
#pragma unroll
    for (int jt = 0; jt < 4; jt++) aw[ss][jt] = (v4f){0.f, 0.f, 0.f, 0.f};
  // prologue: prefetch K chunks it=0 (set A), it=1 (set B), and Q for h=0
  v8s vkA0, vkA1, vkB0, vkB1, vq0, vq1;
  {
    const u16* gk0 =
        Kw + ((size_t)(n * H_N) * S_K + s_base + lane) * D_H + w * 8;
    vkA0 = *(const v8s*)gk0;
    vkA1 = *(const v8s*)(gk0 + 32);
    const u16* gk1 = gk0 + (size_t)64 * D_H;
    vkB0 = *(const v8s*)gk1;
    vkB1 = *(const v8s*)(gk1 + 32);
    const u16* g = Qw + ((size_t)(n * H_N) * L_Q + l0 + lane) * D_H + w * 8;
    vq0 = *(const v8s*)g;
    vq1 = *(const v8s*)(g + 32);
  }
  v8s aq0, aq1;
  float rr[4];
  for (int h = 0; h < H_N; ++h) {
    const int hp = h & 1;  // LDS buffer parity for Q (address only)
#pragma unroll
    for (int ss = 0; ss < 4; ++ss) {  // static: aw indices compile-time
      const int p = ss & 1;           // (h*4+ss)&1 == ss&1, compile-time
      // stage current chunk from its reg set (A = even ss, B = odd ss)
      if (ss == 0) {
        *(v8s*)(Qs[hp] + w * 520 + lane * 8) = vq0;
        *(v8s*)(Qs[hp] + (w + 4) * 520 + lane * 8) = vq1;
      }
      if ((ss & 1) == 0) {
        *(v8s*)(Ks[p] + w * 520 + lane * 8) = vkA0;
        *(v8s*)(Ks[p] + (w + 4) * 520 + lane * 8) = vkA1;
      } else {
        *(v8s*)(Ks[p] + w * 520 + lane * 8) = vkB0;
        *(v8s*)(Ks[p] + (w + 4) * 520 + lane * 8) = vkB1;
      }
      __syncthreads();
      // refill the just-staged set with chunk it+2 (and Q for h+1 at ss==2)
      const int it2 = h * 4 + ss + 2;
      if (it2 < 32) {
        const int h2 = it2 >> 2, ss2 = it2 & 3;
        const u16* gk =
            Kw +
            ((size_t)(n * H_N + h2) * S_K + s_base + ss2 * 64 + lane) * D_H +
            w * 8;
        if ((ss & 1) == 0) {
          vkA0 = *(const v8s*)gk;
          vkA1 = *(const v8s*)(gk + 32);
        } else {
          vkB0 = *(const v8s*)gk;
          vkB1 = *(const v8s*)(gk + 32);
        }
        if (ss2 == 0) {
          const u16* g =
              Qw + ((size_t)(n * H_N + h2) * L_Q + l0 + lane) * D_H + w * 8;
          vq0 = *(const v8s*)g;
          vq1 = *(const v8s*)(g + 32);
        }
      }
      if (ss == 0) {
        aq0 = *(const v8s*)(Qs[hp] + q * 520 + (w * 16 + c) * 8);
        aq1 = *(const v8s*)(Qs[hp] + (q + 4) * 520 + (w * 16 + c) * 8);
#pragma unroll
        for (int r = 0; r < 4; r++)
          rr[r] = Rbuf[(size_t)(n * H_N + h) * L_Q + l0 + w * 16 + q * 4 + r];
      }
#pragma unroll
      for (int jt = 0; jt < 4; jt++) {
        const v8s bk0 = *(const v8s*)(Ks[p] + q * 520 + (jt * 16 + c) * 8);
        const v8s bk1 =
            *(const v8s*)(Ks[p] + (q + 4) * 520 + (jt * 16 + c) * 8);
        v4f zz = (v4f){0.f, 0.f, 0.f, 0.f};
        zz = MFMA16(aq0, bk0, zz);
        zz = MFMA16(aq1, bk1, zz);
#pragma unroll
        for (int r = 0; r < 4; r++) aw[ss][jt][r] += expfast(zz[r]) * rr[r];
      }
    }
  }
#pragma unroll
  for (int ss = 0; ss < 4; ss++)
#pragma unroll
    for (int jt = 0; jt < 4; jt++)
#pragma unroll
      for (int r = 0; r < 4; r++) {
        const int l = l0 + w * 16 + q * 4 + r;
        const int s = s_base + ss * 64 + jt * 16 + c;
        AW[((size_t)n * L_Q + l) * S_K + s] = aw[ss][jt][r] * 0.125f;
      }
}

extern "C" void kernel_launch(void* const* d_in, const int* in_sizes, int n_in,
                              void* d_out, int out_size, void* d_ws,
                              size_t ws_size, hipStream_t stream) {
  // ws layout (<= 29.7 MB, proven safe at 33.8 in R4)
  char* ws = (char*)d_ws;
  u16* Wallb = (u16*)(ws);                 // 1.57 MB
  u16* Woutb = (u16*)(ws + 1572864);       // 0.52 MB
  u16* biasb = (u16*)(ws + 2097152);       // 3 KB
  u16* boutb = (u16*)(ws + 2100224);       // 1 KB
  u16* rel_ub = (u16*)(ws + 2101248);      // 1 KB
  u16* Qw = (u16*)(ws + 4194304);          // 8 MB (N,H,L,D)
  u16* Kw = (u16*)(ws + 12582912);         // 8 MB (N,H,S,D)
  u16* Vt = (u16*)(ws + 20971520);         // 8 MB (N,H,D,S)
  float* Rbuf = (float*)(ws + 29360128);   // 256 KB (N*H, L)

  // scratch inside d_out's attw region (67 MB; overwritten by attw_k LAST)
  float* out = (float*)d_out;
  char* sc = (char*)d_out + 16777216;
  u16* qb = (u16*)(sc);              // 8 MB converted query
  u16* kb = (u16*)(sc + 8388608);    // 8 MB converted key
  u16* vb = (u16*)(sc + 16777216);   // 8 MB converted value
  u16* Actx = (u16*)(sc + 25165824); // 8 MB context (L*4+n, E)
  float* AW = out + (size_t)L_Q * N_B * E_D;

  Cvt8 a;
  a.s[0] = (const float*)d_in[0];  a.d[0] = qb;      // query
  a.s[1] = (const float*)d_in[1];  a.d[1] = kb;      // key
  a.s[2] = (const float*)d_in[2];  a.d[2] = vb;      // value
  a.s[3] = (const float*)d_in[4];  a.d[3] = Wallb;   // in_proj_weight
  a.s[4] = (const float*)d_in[6];  a.d[4] = Woutb;   // out_w
  a.s[5] = (const float*)d_in[5];  a.d[5] = biasb;   // in_proj_bias
  a.s[6] = (const float*)d_in[7];  a.d[6] = boutb;   // out_b
  a.s[7] = (const float*)d_in[9];  a.d[7] = rel_ub;  // rel_u
  // d_in[3] sin_pos_enc, d_in[8] rel_proj_w, d_in[10] rel_v: algebraically out

  hipLaunchKernelGGL(cvt_k, dim3(13315), dim3(256), 0, stream, a);
  hipLaunchKernelGGL(gemm_qkv, dim3(64, 4, 3), dim3(256), 0, stream, qb, kb,
                     vb, Wallb, biasb, rel_ub, Qw, Kw, Vt);
  hipLaunchKernelGGL(flash_pv, dim3(512), dim3(256), 0, stream, Qw, Kw, Vt,
                     Actx, Rbuf);
  hipLaunchKernelGGL(gemm_out, dim3(64, 4, 1), dim3(256), 0, stream, Actx,
                     Woutb, boutb, out);
  hipLaunchKernelGGL(attw_k, dim3(8, 32, 4), dim3(256), 0, stream, Qw, Kw,
                     Rbuf, AW);
}